// Round 9
// baseline (71627.460 us; speedup 1.0000x reference)
//
#include <hip/hip_runtime.h>
#include <stdint.h>

// ---------------------------------------------------------------------------
// RnnSampler: 128 sequential steps. JAX threefry PRNG, PARTITIONABLE mode
// (verified r2). N=256, E=256, V=32000, steps=128.
// r9 = r8 with ONE change: k_logits __launch_bounds__(512,2) -> (512,1).
// Theory: (512,2) caps VGPR at 128; r7/r8's prefetch registers overflowed the
// cap -> hot-loop spill -> 3.4x. Grid=250 <= 256 CUs means the cap bought
// nothing (1 block/CU either way). Lifting it should make reg-prefetch
// spill-free and hide staging latency under the FMA block.
// ---------------------------------------------------------------------------

#define STEPS 128
#define NS    256
#define EDIM  256
#define VDIM  32000

// Threefry-2x32, 20 rounds (Random123 / JAX-compatible)
__host__ __device__ __forceinline__ void tf2x32(uint32_t k0, uint32_t k1,
                                                uint32_t c0, uint32_t c1,
                                                uint32_t& o0, uint32_t& o1) {
  const uint32_t ks2 = k0 ^ k1 ^ 0x1BD11BDAu;
  uint32_t x0 = c0 + k0, x1 = c1 + k1;
#define TF_R(r) { x0 += x1; x1 = (x1 << (r)) | (x1 >> (32 - (r))); x1 ^= x0; }
  TF_R(13) TF_R(15) TF_R(26) TF_R(6)
  x0 += k1;  x1 += ks2 + 1u;
  TF_R(17) TF_R(29) TF_R(16) TF_R(24)
  x0 += ks2; x1 += k0 + 2u;
  TF_R(13) TF_R(15) TF_R(26) TF_R(6)
  x0 += k0;  x1 += k1 + 3u;
  TF_R(17) TF_R(29) TF_R(16) TF_R(24)
  x0 += k1;  x1 += ks2 + 4u;
  TF_R(13) TF_R(15) TF_R(26) TF_R(6)
  x0 += ks2; x1 += k0 + 5u;
#undef TF_R
  o0 = x0; o1 = x1;
}

__device__ __forceinline__ unsigned long long shflx64(unsigned long long v, int m) {
  int lo = __shfl_xor((int)(uint32_t)v, m, 64);
  int hi = __shfl_xor((int)(uint32_t)(v >> 32), m, 64);
  return ((unsigned long long)(uint32_t)hi << 32) | (unsigned long long)(uint32_t)lo;
}

// ---------------------------------------------------------------------------
// k_hidden: C[256,512] = relu(h[256,256] @ W1[512,256]^T + b1)  (r5 verbatim)
// ---------------------------------------------------------------------------
__global__ __launch_bounds__(256) void k_hidden(
    const float* __restrict__ A,
    const float* __restrict__ B,
    const float* __restrict__ bias,
    float* __restrict__ C)
{
  __shared__ float At[16][68];
  __shared__ float Bt[16][68];
  const int tid = threadIdx.x;
  const int tx = tid & 15, ty = tid >> 4;
  const int n0 = blockIdx.y * 64;
  const int v0 = blockIdx.x * 64;
  const int r_st = tid >> 2, c4_st = (tid & 3) << 2;
  float acc[4][4] = {};

  {
    float4 a = *(const float4*)(A + (size_t)(n0 + r_st) * 256 + c4_st);
    float4 b = *(const float4*)(B + (size_t)(v0 + r_st) * 256 + c4_st);
    At[c4_st + 0][r_st] = a.x; At[c4_st + 1][r_st] = a.y;
    At[c4_st + 2][r_st] = a.z; At[c4_st + 3][r_st] = a.w;
    Bt[c4_st + 0][r_st] = b.x; Bt[c4_st + 1][r_st] = b.y;
    Bt[c4_st + 2][r_st] = b.z; Bt[c4_st + 3][r_st] = b.w;
  }
  __syncthreads();

  for (int kk = 0; kk < 256; kk += 16) {
    float4 pa, pb;
    if (kk < 240) {
      pa = *(const float4*)(A + (size_t)(n0 + r_st) * 256 + kk + 16 + c4_st);
      pb = *(const float4*)(B + (size_t)(v0 + r_st) * 256 + kk + 16 + c4_st);
    }
#pragma unroll
    for (int k = 0; k < 16; k++) {
      float af[4], bf[4];
      *(float4*)af = *(const float4*)&At[k][ty * 4];
      *(float4*)bf = *(const float4*)&Bt[k][tx * 4];
#pragma unroll
      for (int a = 0; a < 4; a++)
#pragma unroll
        for (int b = 0; b < 4; b++)
          acc[a][b] = fmaf(af[a], bf[b], acc[a][b]);
    }
    __syncthreads();
    if (kk < 240) {
      At[c4_st + 0][r_st] = pa.x; At[c4_st + 1][r_st] = pa.y;
      At[c4_st + 2][r_st] = pa.z; At[c4_st + 3][r_st] = pa.w;
      Bt[c4_st + 0][r_st] = pb.x; Bt[c4_st + 1][r_st] = pb.y;
      Bt[c4_st + 2][r_st] = pb.z; Bt[c4_st + 3][r_st] = pb.w;
    }
    __syncthreads();
  }
#pragma unroll
  for (int a = 0; a < 4; a++) {
    int r = n0 + ty * 4 + a;
#pragma unroll
    for (int b = 0; b < 4; b++) {
      int v = v0 + tx * 4 + b;
      C[(size_t)r * 512 + v] = fmaxf(acc[a][b] + bias[v], 0.0f);
    }
  }
}

// ---------------------------------------------------------------------------
// k_logits: 250 blocks x 512 thr, tile M=256 x N=128, K=512. 8x8 per-thread.
// SINGLE LDS buffer, 2 barriers/chunk; next-chunk loads issued to registers
// before the FMA block. launch_bounds (512,1): VGPR cap 256 -> no spill.
// ---------------------------------------------------------------------------
__global__ __launch_bounds__(512, 1) void k_logits(
    const float* __restrict__ A,      // hidden [256][512]
    const float* __restrict__ B,      // W2 [32000][512]
    const float* __restrict__ bias,   // b2 [32000]
    unsigned long long* __restrict__ part,  // [256][250]
    uint32_t key0, uint32_t key1)
{
  __shared__ float At[16][260];
  __shared__ float Bt[16][132];
  const int tid = threadIdx.x;
  const int tx = tid & 15;        // col: v0 + q*64 + 4*tx + j
  const int ty = tid >> 4;        // rows 8*ty .. 8*ty+7   (ty 0..31)
  const int v0 = blockIdx.x * 128;
  // staging coords
  const int rA0 = (tid * 2) >> 2,     kA0 = (tid * 2) & 3;       // A: 1024 f4
  const int rA1 = (tid * 2 + 1) >> 2, kA1 = (tid * 2 + 1) & 3;
  const int cB = tid >> 2, kB = tid & 3;                          // B: 512 f4
  float acc[8][2][4] = {};        // [a][q][j] = 64

  // stage chunk 0 directly
  {
    float4 a0 = *(const float4*)(A + (size_t)rA0 * 512 + 4 * kA0);
    float4 a1 = *(const float4*)(A + (size_t)rA1 * 512 + 4 * kA1);
    float4 b  = *(const float4*)(B + (size_t)(v0 + cB) * 512 + 4 * kB);
    At[4 * kA0 + 0][rA0] = a0.x; At[4 * kA0 + 1][rA0] = a0.y;
    At[4 * kA0 + 2][rA0] = a0.z; At[4 * kA0 + 3][rA0] = a0.w;
    At[4 * kA1 + 0][rA1] = a1.x; At[4 * kA1 + 1][rA1] = a1.y;
    At[4 * kA1 + 2][rA1] = a1.z; At[4 * kA1 + 3][rA1] = a1.w;
    Bt[4 * kB + 0][cB] = b.x; Bt[4 * kB + 1][cB] = b.y;
    Bt[4 * kB + 2][cB] = b.z; Bt[4 * kB + 3][cB] = b.w;
  }
  __syncthreads();

  for (int ch = 0; ch < 32; ch++) {
    float4 pa0, pa1, pb0;
    if (ch < 31) {  // issue next-chunk loads; latency hides under FMA block
      const int koff = (ch + 1) * 16;
      pa0 = *(const float4*)(A + (size_t)rA0 * 512 + koff + 4 * kA0);
      pa1 = *(const float4*)(A + (size_t)rA1 * 512 + koff + 4 * kA1);
      pb0 = *(const float4*)(B + (size_t)(v0 + cB) * 512 + koff + 4 * kB);
    }
#pragma unroll
    for (int k = 0; k < 16; k++) {
      float af[8], bf[2][4];
      *(float4*)&af[0] = *(const float4*)&At[k][8 * ty];
      *(float4*)&af[4] = *(const float4*)&At[k][8 * ty + 4];
      *(float4*)&bf[0][0] = *(const float4*)&Bt[k][4 * tx];
      *(float4*)&bf[1][0] = *(const float4*)&Bt[k][64 + 4 * tx];
#pragma unroll
      for (int a = 0; a < 8; a++)
#pragma unroll
        for (int q = 0; q < 2; q++)
#pragma unroll
          for (int j = 0; j < 4; j++)
            acc[a][q][j] = fmaf(af[a], bf[q][j], acc[a][q][j]);
    }
    __syncthreads();            // reads of this chunk done
    if (ch < 31) {              // write prefetched regs into the (single) buffer
      At[4 * kA0 + 0][rA0] = pa0.x; At[4 * kA0 + 1][rA0] = pa0.y;
      At[4 * kA0 + 2][rA0] = pa0.z; At[4 * kA0 + 3][rA0] = pa0.w;
      At[4 * kA1 + 0][rA1] = pa1.x; At[4 * kA1 + 1][rA1] = pa1.y;
      At[4 * kA1 + 2][rA1] = pa1.z; At[4 * kA1 + 3][rA1] = pa1.w;
      Bt[4 * kB + 0][cB] = pb0.x; Bt[4 * kB + 1][cB] = pb0.y;
      Bt[4 * kB + 2][cB] = pb0.z; Bt[4 * kB + 3][cB] = pb0.w;
    }
    __syncthreads();            // writes visible before next chunk's reads
  }

  // epilogue: gumbel + per-row argmax; reduce across the 16 tx lanes via shfl
#pragma unroll
  for (int a = 0; a < 8; a++) {
    const int r = 8 * ty + a;
    unsigned long long best = 0ull;
#pragma unroll
    for (int q = 0; q < 2; q++)
#pragma unroll
      for (int j = 0; j < 4; j++) {
        const int v = v0 + 64 * q + 4 * tx + j;
        const uint32_t p = (uint32_t)r * 32000u + (uint32_t)v;
        uint32_t o0, o1;
        tf2x32(key0, key1, 0u, p, o0, o1);
        const uint32_t bits = o0 ^ o1;
        float f = __uint_as_float((bits >> 9) | 0x3f800000u) - 1.0f;
        float u = fmaxf(f, 1.17549435e-38f);
        float g = -logf(-logf(u));
        float val = acc[a][q][j] + bias[v] + g;
        uint32_t uv = __float_as_uint(val);
        uv = (uv & 0x80000000u) ? ~uv : (uv | 0x80000000u);
        unsigned long long pk =
            ((unsigned long long)uv << 32) |
            (unsigned long long)(0xFFFFFFFFu - (uint32_t)v);
        best = (pk > best) ? pk : best;
      }
#pragma unroll
    for (int m = 1; m < 16; m <<= 1) {
      unsigned long long o = shflx64(best, m);
      best = (o > best) ? o : best;
    }
    if (tx == 0) part[(size_t)r * 250 + blockIdx.x] = best;
  }
}

// ---------------------------------------------------------------------------
// k_gates: token reduce (250 partials) + embed gather + full-K gates GEMM +
// fused LSTM update. grid (16 rowgrps, 8 colgrps), 256 thr.  (r5 verbatim)
// ---------------------------------------------------------------------------
__global__ __launch_bounds__(256) void k_gates(
    const unsigned long long* __restrict__ part,  // [256][250]
    const float* __restrict__ emb,
    const float* __restrict__ h,
    const float* __restrict__ Wp,
    const float* __restrict__ bcatp,
    float* __restrict__ c,
    float* __restrict__ hn,
    int* __restrict__ out, int t)
{
  __shared__ float At[16][520];
  __shared__ float Bt[16][132];
  __shared__ unsigned long long red2[16][17];
  __shared__ int tok_s[16];
  const int tid = threadIdx.x;
  const int tx = tid & 31, ty = tid >> 5;
  const int R0 = blockIdx.x * 16;
  const int C0 = blockIdx.y * 128;
  float acc[2][4] = {};

  {
    const int rw = tid >> 4, il = tid & 15;
    unsigned long long b = 0ull;
    for (int i = il; i < 250; i += 16) {
      unsigned long long x = part[(size_t)(R0 + rw) * 250 + i];
      b = (x > b) ? x : b;
    }
    red2[rw][il] = b;
  }
  __syncthreads();
  if (tid < 16) {
    unsigned long long b = 0ull;
#pragma unroll
    for (int i = 0; i < 16; i++) {
      unsigned long long x = red2[tid][i];
      b = (x > b) ? x : b;
    }
    int tok = (int)(0xFFFFFFFFu - (uint32_t)(b & 0xFFFFFFFFu));
    tok_s[tid] = tok;
    if (blockIdx.y == 0) out[(size_t)(R0 + tid) * STEPS + t] = tok;
  }
  __syncthreads();

#pragma unroll
  for (int i = 0; i < 8; i++) {
    int f = tid + 256 * i;
    int r = f >> 7, k4 = f & 127;
    const float* src = (k4 < 64)
        ? (emb + (size_t)tok_s[r] * 256 + 4 * k4)
        : (h + (size_t)(R0 + r) * 256 + 4 * (k4 - 64));
    *(float4*)&At[r][4 * k4] = *(const float4*)src;
  }

#pragma unroll
  for (int i = 0; i < 2; i++) {
    int f = tid + 256 * i;
    int cc = f >> 2, kq = f & 3;
    float4 w = *(const float4*)(Wp + (size_t)(C0 + cc) * 512 + 4 * kq);
    Bt[4 * kq + 0][cc] = w.x; Bt[4 * kq + 1][cc] = w.y;
    Bt[4 * kq + 2][cc] = w.z; Bt[4 * kq + 3][cc] = w.w;
  }
  __syncthreads();

  for (int ch = 0; ch < 32; ch++) {
    float4 pf[2];
    if (ch < 31) {
#pragma unroll
      for (int i = 0; i < 2; i++) {
        int f = tid + 256 * i;
        int cc = f >> 2, kq = f & 3;
        pf[i] = *(const float4*)(Wp + (size_t)(C0 + cc) * 512 + (ch + 1) * 16 + 4 * kq);
      }
    }
#pragma unroll
    for (int k = 0; k < 16; k++) {
      float af0 = At[2 * ty + 0][16 * ch + k];
      float af1 = At[2 * ty + 1][16 * ch + k];
      float4 bf = *(const float4*)&Bt[k][4 * tx];
      acc[0][0] = fmaf(af0, bf.x, acc[0][0]);
      acc[0][1] = fmaf(af0, bf.y, acc[0][1]);
      acc[0][2] = fmaf(af0, bf.z, acc[0][2]);
      acc[0][3] = fmaf(af0, bf.w, acc[0][3]);
      acc[1][0] = fmaf(af1, bf.x, acc[1][0]);
      acc[1][1] = fmaf(af1, bf.y, acc[1][1]);
      acc[1][2] = fmaf(af1, bf.z, acc[1][2]);
      acc[1][3] = fmaf(af1, bf.w, acc[1][3]);
    }
    __syncthreads();
    if (ch < 31) {
#pragma unroll
      for (int i = 0; i < 2; i++) {
        int f = tid + 256 * i;
        int cc = f >> 2, kq = f & 3;
        Bt[4 * kq + 0][cc] = pf[i].x; Bt[4 * kq + 1][cc] = pf[i].y;
        Bt[4 * kq + 2][cc] = pf[i].z; Bt[4 * kq + 3][cc] = pf[i].w;
      }
    }
    __syncthreads();
  }

  const int e = (C0 >> 2) + tx;
  float4 bb = *(const float4*)(bcatp + C0 + 4 * tx);
#pragma unroll
  for (int a = 0; a < 2; a++) {
    const int r = R0 + 2 * ty + a;
    float gi = acc[a][0] + bb.x;
    float gf = acc[a][1] + bb.y;
    float gg = acc[a][2] + bb.z;
    float go = acc[a][3] + bb.w;
    float si = 1.0f / (1.0f + expf(-gi));
    float sf = 1.0f / (1.0f + expf(-gf));
    float so = 1.0f / (1.0f + expf(-go));
    float cv = sf * c[(size_t)r * 256 + e] + si * tanhf(gg);
    c[(size_t)r * 256 + e] = cv;
    hn[(size_t)r * 256 + e] = so * tanhf(cv);
  }
}

__global__ __launch_bounds__(256) void k_init(
    float* __restrict__ h, float* __restrict__ c,
    const float* __restrict__ init_h)
{
  const int n = blockIdx.x, e = threadIdx.x;
  const float v = init_h[e];
  h[(size_t)n * 256 + e] = v;
  c[(size_t)n * 256 + e] = v;
}

__global__ __launch_bounds__(256) void k_prep(
    float* __restrict__ Wp, float* __restrict__ bcatp,
    const float* __restrict__ W_ih, const float* __restrict__ W_hh,
    const float* __restrict__ b_ih, const float* __restrict__ b_hh)
{
  const int q = blockIdx.x, k = threadIdx.x;
  const int e = q >> 2, g = q & 3;
  const int src = g * 256 + e;
  Wp[(size_t)q * 512 + k]       = W_ih[(size_t)src * 256 + k];
  Wp[(size_t)q * 512 + 256 + k] = W_hh[(size_t)src * 256 + k];
  if (k == 0) bcatp[q] = b_ih[src] + b_hh[src];
}

extern "C" void kernel_launch(void* const* d_in, const int* in_sizes, int n_in,
                              void* d_out, int out_size, void* d_ws, size_t ws_size,
                              hipStream_t stream) {
  const float* init_h      = (const float*)d_in[2];
  const float* token_embed = (const float*)d_in[3];
  const float* W_ih        = (const float*)d_in[4];
  const float* W_hh        = (const float*)d_in[5];
  const float* b_ih        = (const float*)d_in[6];
  const float* b_hh        = (const float*)d_in[7];
  const float* W1          = (const float*)d_in[8];
  const float* b1          = (const float*)d_in[9];
  const float* W2          = (const float*)d_in[10];
  const float* b2          = (const float*)d_in[11];
  int* out = (int*)d_out;

  char* ws = (char*)d_ws;
  float* h0    = (float*)(ws + 0);        // 256 KB
  float* h1    = (float*)(ws + 262144);   // 256 KB
  float* c     = (float*)(ws + 524288);   // 256 KB
  float* Wp    = (float*)(ws + 786432);   //   2 MB
  float* bcatp = (float*)(ws + 2883584);  //   4 KB
  unsigned long long* part = (unsigned long long*)(ws + 2887680); // 500 KB [256][250]
  float* hidden = (float*)(ws + 3399680); // 512 KB
  // total < 4 MB

  uint32_t k0[STEPS], k1[STEPS];
  for (uint32_t t = 0; t < STEPS; t++) tf2x32(0u, 42u, 0u, t, k0[t], k1[t]);

  k_init<<<NS, 256, 0, stream>>>(h0, c, init_h);
  k_prep<<<1024, 256, 0, stream>>>(Wp, bcatp, W_ih, W_hh, b_ih, b_hh);
  k_hidden<<<dim3(8, 4), 256, 0, stream>>>(h0, W1, b1, hidden);

  for (int t = 0; t < STEPS; t++) {
    float* hc = (t & 1) ? h1 : h0;
    float* hx = (t & 1) ? h0 : h1;
    k_logits<<<250, 512, 0, stream>>>(hidden, W2, b2, part, k0[t], k1[t]);
    k_gates<<<dim3(16, 8), 256, 0, stream>>>(part, token_embed, hc, Wp, bcatp,
                                             c, hx, out, t);
    if (t < STEPS - 1)
      k_hidden<<<dim3(8, 4), 256, 0, stream>>>(hx, W1, b1, hidden);
  }
}

// Round 10
// 20481.483 us; speedup vs baseline: 3.4972x; 3.4972x over previous
//
#include <hip/hip_runtime.h>
#include <stdint.h>

// ---------------------------------------------------------------------------
// RnnSampler: 128 sequential steps. JAX threefry PRNG, PARTITIONABLE mode
// (verified r2). N=256, E=256, V=32000, steps=128.
// r10: k_logits rewritten around __builtin_amdgcn_global_load_lds (m97-proven
// schedule): k-major operands (hiddenT + one-time W2T transpose), linear LDS
// dests, double-buffered LDS, async issue-before-compute, NO staging VGPRs
// (register prefetch in this kernel = proven 3.4x poison, r7/r8/r9).
// 256 thr, 128x128 tile, 64 acc, grid (250,2) -> 2 blocks/CU.
// Host falls back to a stage-direct variant if ws_size < 69.5 MB.
// ---------------------------------------------------------------------------

#define STEPS 128
#define NS    256
#define EDIM  256
#define VDIM  32000

// Threefry-2x32, 20 rounds (Random123 / JAX-compatible)
__host__ __device__ __forceinline__ void tf2x32(uint32_t k0, uint32_t k1,
                                                uint32_t c0, uint32_t c1,
                                                uint32_t& o0, uint32_t& o1) {
  const uint32_t ks2 = k0 ^ k1 ^ 0x1BD11BDAu;
  uint32_t x0 = c0 + k0, x1 = c1 + k1;
#define TF_R(r) { x0 += x1; x1 = (x1 << (r)) | (x1 >> (32 - (r))); x1 ^= x0; }
  TF_R(13) TF_R(15) TF_R(26) TF_R(6)
  x0 += k1;  x1 += ks2 + 1u;
  TF_R(17) TF_R(29) TF_R(16) TF_R(24)
  x0 += ks2; x1 += k0 + 2u;
  TF_R(13) TF_R(15) TF_R(26) TF_R(6)
  x0 += k0;  x1 += k1 + 3u;
  TF_R(17) TF_R(29) TF_R(16) TF_R(24)
  x0 += k1;  x1 += ks2 + 4u;
  TF_R(13) TF_R(15) TF_R(26) TF_R(6)
  x0 += ks2; x1 += k0 + 5u;
#undef TF_R
  o0 = x0; o1 = x1;
}

__device__ __forceinline__ unsigned long long shflx64(unsigned long long v, int m) {
  int lo = __shfl_xor((int)(uint32_t)v, m, 64);
  int hi = __shfl_xor((int)(uint32_t)(v >> 32), m, 64);
  return ((unsigned long long)(uint32_t)hi << 32) | (unsigned long long)(uint32_t)lo;
}

// async global->LDS, 16B per lane, no VGPR roundtrip
__device__ __forceinline__ void gl16(const float* g, float* l) {
  __builtin_amdgcn_global_load_lds(
      (const __attribute__((address_space(1))) void*)g,
      (__attribute__((address_space(3))) void*)l, 16, 0, 0);
}

// ---------------------------------------------------------------------------
// k_hidden: hiddenT[512 k][256 rows] = relu(h[256,256] @ W1[512,256]^T + b1)^T
// (r5 GEMM verbatim; only the store is transposed -> k-major output)
// ---------------------------------------------------------------------------
__global__ __launch_bounds__(256) void k_hidden(
    const float* __restrict__ A,    // h [256][256]
    const float* __restrict__ B,    // W1 [512][256]
    const float* __restrict__ bias, // b1 [512]
    float* __restrict__ CT)         // hiddenT [512][256]
{
  __shared__ float At[16][68];
  __shared__ float Bt[16][68];
  const int tid = threadIdx.x;
  const int tx = tid & 15, ty = tid >> 4;
  const int n0 = blockIdx.y * 64;   // rows (M)
  const int v0 = blockIdx.x * 64;   // cols (k of hiddenT)
  const int r_st = tid >> 2, c4_st = (tid & 3) << 2;
  float acc[4][4] = {};

  {
    float4 a = *(const float4*)(A + (size_t)(n0 + r_st) * 256 + c4_st);
    float4 b = *(const float4*)(B + (size_t)(v0 + r_st) * 256 + c4_st);
    At[c4_st + 0][r_st] = a.x; At[c4_st + 1][r_st] = a.y;
    At[c4_st + 2][r_st] = a.z; At[c4_st + 3][r_st] = a.w;
    Bt[c4_st + 0][r_st] = b.x; Bt[c4_st + 1][r_st] = b.y;
    Bt[c4_st + 2][r_st] = b.z; Bt[c4_st + 3][r_st] = b.w;
  }
  __syncthreads();

  for (int kk = 0; kk < 256; kk += 16) {
    float4 pa, pb;
    if (kk < 240) {
      pa = *(const float4*)(A + (size_t)(n0 + r_st) * 256 + kk + 16 + c4_st);
      pb = *(const float4*)(B + (size_t)(v0 + r_st) * 256 + kk + 16 + c4_st);
    }
#pragma unroll
    for (int k = 0; k < 16; k++) {
      float af[4], bf[4];
      *(float4*)af = *(const float4*)&At[k][ty * 4];
      *(float4*)bf = *(const float4*)&Bt[k][tx * 4];
#pragma unroll
      for (int a = 0; a < 4; a++)
#pragma unroll
        for (int b = 0; b < 4; b++)
          acc[a][b] = fmaf(af[a], bf[b], acc[a][b]);
    }
    __syncthreads();
    if (kk < 240) {
      At[c4_st + 0][r_st] = pa.x; At[c4_st + 1][r_st] = pa.y;
      At[c4_st + 2][r_st] = pa.z; At[c4_st + 3][r_st] = pa.w;
      Bt[c4_st + 0][r_st] = pb.x; Bt[c4_st + 1][r_st] = pb.y;
      Bt[c4_st + 2][r_st] = pb.z; Bt[c4_st + 3][r_st] = pb.w;
    }
    __syncthreads();
  }
  // transposed store: hiddenT[v][n0+4ty .. +3] as one float4 per b
#pragma unroll
  for (int b = 0; b < 4; b++) {
    const int v = v0 + tx * 4 + b;
    const float bv = bias[v];
    float4 o;
    o.x = fmaxf(acc[0][b] + bv, 0.0f);
    o.y = fmaxf(acc[1][b] + bv, 0.0f);
    o.z = fmaxf(acc[2][b] + bv, 0.0f);
    o.w = fmaxf(acc[3][b] + bv, 0.0f);
    *(float4*)(CT + (size_t)v * 256 + n0 + ty * 4) = o;
  }
}

// W2 [32000][512] -> W2T [512][32000], 32x32 LDS tiles. grid (1000,16), 256 thr
__global__ __launch_bounds__(256) void k_tr_w2(
    const float* __restrict__ W2, float* __restrict__ W2T)
{
  __shared__ float t[32][33];
  const int R0 = blockIdx.x * 32;   // vocab
  const int C0 = blockIdx.y * 32;   // k
  const int tid = threadIdx.x;
#pragma unroll
  for (int i = 0; i < 4; i++) {
    int f = tid + 256 * i;
    int r = f >> 5, c = f & 31;
    t[r][c] = W2[(size_t)(R0 + r) * 512 + C0 + c];
  }
  __syncthreads();
#pragma unroll
  for (int i = 0; i < 4; i++) {
    int f = tid + 256 * i;
    int r = f >> 5, c = f & 31;
    W2T[(size_t)(C0 + r) * 32000 + R0 + c] = t[c][r];
  }
}

// ---------------------------------------------------------------------------
// k_logitsA (fast path): grid (250,2) x 256 thr, tile 128(M) x 128(N), K=512.
// Double-buffered LDS filled by global_load_lds (async, issued before the
// FMA block, no staging VGPRs). Fused gumbel + per-row argmax partials.
// ---------------------------------------------------------------------------
__global__ __launch_bounds__(256) void k_logitsA(
    const float* __restrict__ hT,    // hiddenT [512][256]
    const float* __restrict__ W2T,   // [512][32000]
    const float* __restrict__ bias,  // b2 [32000]
    unsigned long long* __restrict__ part,  // [256][250]
    uint32_t key0, uint32_t key1)
{
  __shared__ float At[2][16][128];
  __shared__ float Bt[2][16][128];
  const int tid = threadIdx.x;
  const int tx = tid & 15;        // col: v0 + q*64 + 4*tx + j (q<2, j<4)
  const int ty = tid >> 4;        // rows n0 + 8*ty .. +7  (ty 0..15)
  const int v0 = blockIdx.x * 128;
  const int n0 = blockIdx.y * 128;
  const int r0 = tid >> 5, c0 = tid & 31;  // staging: 32 f4-chunks per k-row
  float acc[8][2][4] = {};        // 64

  // chunk 0 -> buffer 0
  {
    gl16(hT  + (size_t)(r0)      * 256   + n0 + 4 * c0, &At[0][r0][4 * c0]);
    gl16(hT  + (size_t)(r0 + 8)  * 256   + n0 + 4 * c0, &At[0][r0 + 8][4 * c0]);
    gl16(W2T + (size_t)(r0)      * 32000 + v0 + 4 * c0, &Bt[0][r0][4 * c0]);
    gl16(W2T + (size_t)(r0 + 8)  * 32000 + v0 + 4 * c0, &Bt[0][r0 + 8][4 * c0]);
  }
  __syncthreads();

  for (int ch = 0; ch < 32; ch++) {
    const int cur = ch & 1;
    if (ch < 31) {  // async-issue next chunk into the other buffer
      const int kk = (ch + 1) * 16;
      gl16(hT  + (size_t)(kk + r0)     * 256   + n0 + 4 * c0, &At[cur ^ 1][r0][4 * c0]);
      gl16(hT  + (size_t)(kk + r0 + 8) * 256   + n0 + 4 * c0, &At[cur ^ 1][r0 + 8][4 * c0]);
      gl16(W2T + (size_t)(kk + r0)     * 32000 + v0 + 4 * c0, &Bt[cur ^ 1][r0][4 * c0]);
      gl16(W2T + (size_t)(kk + r0 + 8) * 32000 + v0 + 4 * c0, &Bt[cur ^ 1][r0 + 8][4 * c0]);
    }
#pragma unroll
    for (int k = 0; k < 16; k++) {
      float af[8], bf[2][4];
      *(float4*)&af[0] = *(const float4*)&At[cur][k][8 * ty];
      *(float4*)&af[4] = *(const float4*)&At[cur][k][8 * ty + 4];
      *(float4*)&bf[0][0] = *(const float4*)&Bt[cur][k][4 * tx];
      *(float4*)&bf[1][0] = *(const float4*)&Bt[cur][k][64 + 4 * tx];
#pragma unroll
      for (int a = 0; a < 8; a++)
#pragma unroll
        for (int q = 0; q < 2; q++)
#pragma unroll
          for (int j = 0; j < 4; j++)
            acc[a][q][j] = fmaf(af[a], bf[q][j], acc[a][q][j]);
    }
    __syncthreads();   // drains vmcnt (next chunk landed during compute)
  }

  // epilogue: gumbel + per-row argmax; shfl-reduce over 16 tx lanes
#pragma unroll
  for (int a = 0; a < 8; a++) {
    const int r = n0 + 8 * ty + a;
    unsigned long long best = 0ull;
#pragma unroll
    for (int q = 0; q < 2; q++)
#pragma unroll
      for (int j = 0; j < 4; j++) {
        const int v = v0 + 64 * q + 4 * tx + j;
        const uint32_t p = (uint32_t)r * 32000u + (uint32_t)v;
        uint32_t o0, o1;
        tf2x32(key0, key1, 0u, p, o0, o1);
        const uint32_t bits = o0 ^ o1;
        float f = __uint_as_float((bits >> 9) | 0x3f800000u) - 1.0f;
        float u = fmaxf(f, 1.17549435e-38f);
        float g = -logf(-logf(u));
        float val = acc[a][q][j] + bias[v] + g;
        uint32_t uv = __float_as_uint(val);
        uv = (uv & 0x80000000u) ? ~uv : (uv | 0x80000000u);
        unsigned long long pk =
            ((unsigned long long)uv << 32) |
            (unsigned long long)(0xFFFFFFFFu - (uint32_t)v);
        best = (pk > best) ? pk : best;
      }
#pragma unroll
    for (int m = 1; m < 16; m <<= 1) {
      unsigned long long o = shflx64(best, m);
      best = (o > best) ? o : best;
    }
    if (tx == 0) part[(size_t)r * 250 + blockIdx.x] = best;
  }
}

// ---------------------------------------------------------------------------
// k_logitsF (fallback, ws too small for W2T): same tile/grid, stage-direct
// (r5-style: load -> immediate LDS write, 2 barriers, NO prefetch).
// A from hiddenT (linear); B transposed in LDS from W2 row-major.
// ---------------------------------------------------------------------------
__global__ __launch_bounds__(256) void k_logitsF(
    const float* __restrict__ hT,    // hiddenT [512][256]
    const float* __restrict__ W2,    // [32000][512]
    const float* __restrict__ bias,
    unsigned long long* __restrict__ part,
    uint32_t key0, uint32_t key1)
{
  __shared__ float At[16][128];
  __shared__ float Bt[16][132];
  const int tid = threadIdx.x;
  const int tx = tid & 15, ty = tid >> 4;
  const int v0 = blockIdx.x * 128;
  const int n0 = blockIdx.y * 128;
  const int r0 = tid >> 5, c0 = tid & 31;   // A staging
  const int cB = tid >> 1, kB2 = tid & 1;   // B staging: 2 f4 per col? no:
  float acc[8][2][4] = {};

  for (int kk = 0; kk < 512; kk += 16) {
    // A: 512 f4 linear, 2/thread
#pragma unroll
    for (int i = 0; i < 2; i++) {
      const int r = r0 + 8 * i;
      float4 a = *(const float4*)(hT + (size_t)(kk + r) * 256 + n0 + 4 * c0);
      *(float4*)&At[r][4 * c0] = a;
    }
    // B: 512 f4 transpose-staged, 2/thread: f = tid + 256*i, c=f>>2, kq=f&3
#pragma unroll
    for (int i = 0; i < 2; i++) {
      const int f = tid + 256 * i;
      const int c = f >> 2, kq = f & 3;
      float4 b = *(const float4*)(W2 + (size_t)(v0 + c) * 512 + kk + 4 * kq);
      Bt[4 * kq + 0][c] = b.x; Bt[4 * kq + 1][c] = b.y;
      Bt[4 * kq + 2][c] = b.z; Bt[4 * kq + 3][c] = b.w;
    }
    __syncthreads();
#pragma unroll
    for (int k = 0; k < 16; k++) {
      float af[8], bf[2][4];
      *(float4*)&af[0] = *(const float4*)&At[k][8 * ty];
      *(float4*)&af[4] = *(const float4*)&At[k][8 * ty + 4];
      *(float4*)&bf[0][0] = *(const float4*)&Bt[k][4 * tx];
      *(float4*)&bf[1][0] = *(const float4*)&Bt[k][64 + 4 * tx];
#pragma unroll
      for (int a = 0; a < 8; a++)
#pragma unroll
        for (int q = 0; q < 2; q++)
#pragma unroll
          for (int j = 0; j < 4; j++)
            acc[a][q][j] = fmaf(af[a], bf[q][j], acc[a][q][j]);
    }
    __syncthreads();
  }

#pragma unroll
  for (int a = 0; a < 8; a++) {
    const int r = n0 + 8 * ty + a;
    unsigned long long best = 0ull;
#pragma unroll
    for (int q = 0; q < 2; q++)
#pragma unroll
      for (int j = 0; j < 4; j++) {
        const int v = v0 + 64 * q + 4 * tx + j;
        const uint32_t p = (uint32_t)r * 32000u + (uint32_t)v;
        uint32_t o0, o1;
        tf2x32(key0, key1, 0u, p, o0, o1);
        const uint32_t bits = o0 ^ o1;
        float f = __uint_as_float((bits >> 9) | 0x3f800000u) - 1.0f;
        float u = fmaxf(f, 1.17549435e-38f);
        float g = -logf(-logf(u));
        float val = acc[a][q][j] + bias[v] + g;
        uint32_t uv = __float_as_uint(val);
        uv = (uv & 0x80000000u) ? ~uv : (uv | 0x80000000u);
        unsigned long long pk =
            ((unsigned long long)uv << 32) |
            (unsigned long long)(0xFFFFFFFFu - (uint32_t)v);
        best = (pk > best) ? pk : best;
      }
#pragma unroll
    for (int m = 1; m < 16; m <<= 1) {
      unsigned long long o = shflx64(best, m);
      best = (o > best) ? o : best;
    }
    if (tx == 0) part[(size_t)r * 250 + blockIdx.x] = best;
  }
}

// ---------------------------------------------------------------------------
// k_gates: token reduce (250 partials) + embed gather + full-K gates GEMM +
// fused LSTM update. grid (16 rowgrps, 8 colgrps), 256 thr.  (r5 verbatim)
// ---------------------------------------------------------------------------
__global__ __launch_bounds__(256) void k_gates(
    const unsigned long long* __restrict__ part,  // [256][250]
    const float* __restrict__ emb,
    const float* __restrict__ h,
    const float* __restrict__ Wp,
    const float* __restrict__ bcatp,
    float* __restrict__ c,
    float* __restrict__ hn,
    int* __restrict__ out, int t)
{
  __shared__ float At[16][520];
  __shared__ float Bt[16][132];
  __shared__ unsigned long long red2[16][17];
  __shared__ int tok_s[16];
  const int tid = threadIdx.x;
  const int tx = tid & 31, ty = tid >> 5;
  const int R0 = blockIdx.x * 16;
  const int C0 = blockIdx.y * 128;
  float acc[2][4] = {};

  {
    const int rw = tid >> 4, il = tid & 15;
    unsigned long long b = 0ull;
    for (int i = il; i < 250; i += 16) {
      unsigned long long x = part[(size_t)(R0 + rw) * 250 + i];
      b = (x > b) ? x : b;
    }
    red2[rw][il] = b;
  }
  __syncthreads();
  if (tid < 16) {
    unsigned long long b = 0ull;
#pragma unroll
    for (int i = 0; i < 16; i++) {
      unsigned long long x = red2[tid][i];
      b = (x > b) ? x : b;
    }
    int tok = (int)(0xFFFFFFFFu - (uint32_t)(b & 0xFFFFFFFFu));
    tok_s[tid] = tok;
    if (blockIdx.y == 0) out[(size_t)(R0 + tid) * STEPS + t] = tok;
  }
  __syncthreads();

#pragma unroll
  for (int i = 0; i < 8; i++) {
    int f = tid + 256 * i;
    int r = f >> 7, k4 = f & 127;
    const float* src = (k4 < 64)
        ? (emb + (size_t)tok_s[r] * 256 + 4 * k4)
        : (h + (size_t)(R0 + r) * 256 + 4 * (k4 - 64));
    *(float4*)&At[r][4 * k4] = *(const float4*)src;
  }

#pragma unroll
  for (int i = 0; i < 2; i++) {
    int f = tid + 256 * i;
    int cc = f >> 2, kq = f & 3;
    float4 w = *(const float4*)(Wp + (size_t)(C0 + cc) * 512 + 4 * kq);
    Bt[4 * kq + 0][cc] = w.x; Bt[4 * kq + 1][cc] = w.y;
    Bt[4 * kq + 2][cc] = w.z; Bt[4 * kq + 3][cc] = w.w;
  }
  __syncthreads();

  for (int ch = 0; ch < 32; ch++) {
    float4 pf[2];
    if (ch < 31) {
#pragma unroll
      for (int i = 0; i < 2; i++) {
        int f = tid + 256 * i;
        int cc = f >> 2, kq = f & 3;
        pf[i] = *(const float4*)(Wp + (size_t)(C0 + cc) * 512 + (ch + 1) * 16 + 4 * kq);
      }
    }
#pragma unroll
    for (int k = 0; k < 16; k++) {
      float af0 = At[2 * ty + 0][16 * ch + k];
      float af1 = At[2 * ty + 1][16 * ch + k];
      float4 bf = *(const float4*)&Bt[k][4 * tx];
      acc[0][0] = fmaf(af0, bf.x, acc[0][0]);
      acc[0][1] = fmaf(af0, bf.y, acc[0][1]);
      acc[0][2] = fmaf(af0, bf.z, acc[0][2]);
      acc[0][3] = fmaf(af0, bf.w, acc[0][3]);
      acc[1][0] = fmaf(af1, bf.x, acc[1][0]);
      acc[1][1] = fmaf(af1, bf.y, acc[1][1]);
      acc[1][2] = fmaf(af1, bf.z, acc[1][2]);
      acc[1][3] = fmaf(af1, bf.w, acc[1][3]);
    }
    __syncthreads();
    if (ch < 31) {
#pragma unroll
      for (int i = 0; i < 2; i++) {
        int f = tid + 256 * i;
        int cc = f >> 2, kq = f & 3;
        Bt[4 * kq + 0][cc] = pf[i].x; Bt[4 * kq + 1][cc] = pf[i].y;
        Bt[4 * kq + 2][cc] = pf[i].z; Bt[4 * kq + 3][cc] = pf[i].w;
      }
    }
    __syncthreads();
  }

  const int e = (C0 >> 2) + tx;
  float4 bb = *(const float4*)(bcatp + C0 + 4 * tx);
#pragma unroll
  for (int a = 0; a < 2; a++) {
    const int r = R0 + 2 * ty + a;
    float gi = acc[a][0] + bb.x;
    float gf = acc[a][1] + bb.y;
    float gg = acc[a][2] + bb.z;
    float go = acc[a][3] + bb.w;
    float si = 1.0f / (1.0f + expf(-gi));
    float sf = 1.0f / (1.0f + expf(-gf));
    float so = 1.0f / (1.0f + expf(-go));
    float cv = sf * c[(size_t)r * 256 + e] + si * tanhf(gg);
    c[(size_t)r * 256 + e] = cv;
    hn[(size_t)r * 256 + e] = so * tanhf(cv);
  }
}

__global__ __launch_bounds__(256) void k_init(
    float* __restrict__ h, float* __restrict__ c,
    const float* __restrict__ init_h)
{
  const int n = blockIdx.x, e = threadIdx.x;
  const float v = init_h[e];
  h[(size_t)n * 256 + e] = v;
  c[(size_t)n * 256 + e] = v;
}

__global__ __launch_bounds__(256) void k_prep(
    float* __restrict__ Wp, float* __restrict__ bcatp,
    const float* __restrict__ W_ih, const float* __restrict__ W_hh,
    const float* __restrict__ b_ih, const float* __restrict__ b_hh)
{
  const int q = blockIdx.x, k = threadIdx.x;
  const int e = q >> 2, g = q & 3;
  const int src = g * 256 + e;
  Wp[(size_t)q * 512 + k]       = W_ih[(size_t)src * 256 + k];
  Wp[(size_t)q * 512 + 256 + k] = W_hh[(size_t)src * 256 + k];
  if (k == 0) bcatp[q] = b_ih[src] + b_hh[src];
}

extern "C" void kernel_launch(void* const* d_in, const int* in_sizes, int n_in,
                              void* d_out, int out_size, void* d_ws, size_t ws_size,
                              hipStream_t stream) {
  const float* init_h      = (const float*)d_in[2];
  const float* token_embed = (const float*)d_in[3];
  const float* W_ih        = (const float*)d_in[4];
  const float* W_hh        = (const float*)d_in[5];
  const float* b_ih        = (const float*)d_in[6];
  const float* b_hh        = (const float*)d_in[7];
  const float* W1          = (const float*)d_in[8];
  const float* b1          = (const float*)d_in[9];
  const float* W2          = (const float*)d_in[10];
  const float* b2          = (const float*)d_in[11];
  int* out = (int*)d_out;

  char* ws = (char*)d_ws;
  float* h0     = (float*)(ws + 0);        // 256 KB
  float* h1     = (float*)(ws + 262144);   // 256 KB
  float* c      = (float*)(ws + 524288);   // 256 KB
  float* Wp     = (float*)(ws + 786432);   //   2 MB
  float* bcatp  = (float*)(ws + 2883584);  //   4 KB
  unsigned long long* part = (unsigned long long*)(ws + 2887680); // 512 KB
  float* hiddenT = (float*)(ws + 3411968); // 512 KB [512][256]
  float* W2T     = (float*)(ws + 3936256); // 65.536 MB [512][32000]
  const size_t NEED_FAST = 3936256ull + 65536000ull;  // ~69.5 MB
  const bool fast = (ws_size >= NEED_FAST);

  uint32_t k0[STEPS], k1[STEPS];
  for (uint32_t t = 0; t < STEPS; t++) tf2x32(0u, 42u, 0u, t, k0[t], k1[t]);

  k_init<<<NS, 256, 0, stream>>>(h0, c, init_h);
  k_prep<<<1024, 256, 0, stream>>>(Wp, bcatp, W_ih, W_hh, b_ih, b_hh);
  if (fast) k_tr_w2<<<dim3(1000, 16), 256, 0, stream>>>(W2, W2T);
  k_hidden<<<dim3(8, 4), 256, 0, stream>>>(h0, W1, b1, hiddenT);

  for (int t = 0; t < STEPS; t++) {
    float* hc = (t & 1) ? h1 : h0;
    float* hx = (t & 1) ? h0 : h1;
    if (fast)
      k_logitsA<<<dim3(250, 2), 256, 0, stream>>>(hiddenT, W2T, b2, part,
                                                  k0[t], k1[t]);
    else
      k_logitsF<<<dim3(250, 2), 256, 0, stream>>>(hiddenT, W2, b2, part,
                                                  k0[t], k1[t]);
    k_gates<<<dim3(16, 8), 256, 0, stream>>>(part, token_embed, hc, Wp, bcatp,
                                             c, hx, out, t);
    if (t < STEPS - 1)
      k_hidden<<<dim3(8, 4), 256, 0, stream>>>(hx, W1, b1, hiddenT);
  }
}